// Round 1
// 174.686 us; speedup vs baseline: 1.0698x; 1.0698x over previous
//
#include <hip/hip_runtime.h>
#include <cstddef>

constexpr int FIN = 128;
constexpr int EPB = 2048;   // edges per block in bucket passes (391 blocks)
constexpr int BSH = 7;      // bucket shift: 128 nodes per bucket
constexpr int NPB = 128;    // nodes per bucket
constexpr int PACK_SH = 25; // ebuck pack: (dst_local << 25) | src (src < 2^25)

typedef _Float16 half4 __attribute__((ext_vector_type(4)));
typedef _Float16 half8 __attribute__((ext_vector_type(8)));
typedef float floatx4 __attribute__((ext_vector_type(4)));

// ---------------------------------------------------------------------------
// Block-wide (256-thread) exclusive scan; also returns block total.
// Caller must __syncthreads() before reusing wsums.
// ---------------------------------------------------------------------------
__device__ __forceinline__ int block_scan_tot(int v, int tid, int* wsums,
                                              int* tot) {
    int lane = tid & 63, w = tid >> 6;
    int x = v;
#pragma unroll
    for (int off = 1; off < 64; off <<= 1) {
        int y = __shfl_up(x, off, 64);
        if (lane >= off) x += y;
    }
    if (lane == 63) wsums[w] = x;
    __syncthreads();
    int add = 0;
#pragma unroll
    for (int i = 0; i < 4; ++i) add += (i < w) ? wsums[i] : 0;
    *tot = wsums[0] + wsums[1] + wsums[2] + wsums[3];
    return x + add - v;
}

// ---------------------------------------------------------------------------
// MFMA GEMM body (R7): Hh[N,64](fp16) = X[N,K] @ W[K,64]; fused AS/AD (fp32).
// LDS: Xh[64][K+8] fp16 (A), WT[64][K+8] fp16 (B^T). 16B-aligned rows,
// b128 frag reads 2-way bank alias (free). mfma_f32_16x16x32_f16.
// ---------------------------------------------------------------------------
template <int K, typename XT>
__device__ __forceinline__
void gemm_mfma_body(const XT* __restrict__ X, const float* __restrict__ W,
                    const float* __restrict__ ASRC, const float* __restrict__ ADST,
                    _Float16* __restrict__ Hh, float* __restrict__ AS,
                    float* __restrict__ AD, int N, int blk,
                    _Float16* Xh, _Float16* WT) {
    constexpr int LDH = K + 8;
    const int tid = threadIdx.x;
    const int nb = blk * 64;

    if constexpr (sizeof(XT) == 4) {
        constexpr int QPR = K / 4;
        for (int i = tid; i < 64 * QPR; i += 256) {
            int r = i / QPR, q = i % QPR;
            float4 v = make_float4(0.f, 0.f, 0.f, 0.f);
            if (nb + r < N) v = *(const float4*)(X + (size_t)(nb + r) * K + 4 * q);
            half4 h; h[0] = (_Float16)v.x; h[1] = (_Float16)v.y;
            h[2] = (_Float16)v.z; h[3] = (_Float16)v.w;
            *(half4*)(Xh + r * LDH + 4 * q) = h;
        }
    } else {
        constexpr int OPR = K / 8;
        for (int i = tid; i < 64 * OPR; i += 256) {
            int r = i / OPR, o = i % OPR;
            half8 v = {};
            if (nb + r < N) v = *(const half8*)(X + (size_t)(nb + r) * K + 8 * o);
            *(half8*)(Xh + r * LDH + 8 * o) = v;
        }
    }
    for (int i = tid; i < 64 * (K / 4); i += 256) {
        int n = i & 63, kg = i >> 6;
        half4 h;
#pragma unroll
        for (int j = 0; j < 4; ++j)
            h[j] = (_Float16)W[(4 * kg + j) * 64 + n];
        *(half4*)(WT + n * LDH + 4 * kg) = h;
    }
    __syncthreads();

    const int l = tid & 63;
    const int r0 = (tid >> 6) * 16;
    const int n16 = l & 15, quad = l >> 4;

    floatx4 acc[4];
#pragma unroll
    for (int nt = 0; nt < 4; ++nt) acc[nt] = (floatx4){0.f, 0.f, 0.f, 0.f};

#pragma unroll
    for (int k0 = 0; k0 < K; k0 += 32) {
        half8 a = *(const half8*)(Xh + (r0 + n16) * LDH + k0 + quad * 8);
#pragma unroll
        for (int nt = 0; nt < 4; ++nt) {
            half8 b = *(const half8*)(WT + (nt * 16 + n16) * LDH + k0 + quad * 8);
            acc[nt] = __builtin_amdgcn_mfma_f32_16x16x32_f16(a, b, acc[nt], 0, 0, 0);
        }
    }

    float pa[4] = {0.f, 0.f, 0.f, 0.f}, pd[4] = {0.f, 0.f, 0.f, 0.f};
#pragma unroll
    for (int nt = 0; nt < 4; ++nt) {
        float as_v = ASRC[nt * 16 + n16], ad_v = ADST[nt * 16 + n16];
#pragma unroll
        for (int reg = 0; reg < 4; ++reg) {
            pa[reg] += acc[nt][reg] * as_v;
            pd[reg] += acc[nt][reg] * ad_v;
        }
    }
#pragma unroll
    for (int off = 1; off < 16; off <<= 1) {
#pragma unroll
        for (int reg = 0; reg < 4; ++reg) {
            pa[reg] += __shfl_xor(pa[reg], off, 64);
            pd[reg] += __shfl_xor(pd[reg], off, 64);
        }
    }
    if (n16 == 0) {
#pragma unroll
        for (int reg = 0; reg < 4; ++reg) {
            int row = nb + r0 + quad * 4 + reg;
            if (row < N) { AS[row] = pa[reg]; AD[row] = pd[reg]; }
        }
    }

#pragma unroll
    for (int nt = 0; nt < 4; ++nt)
#pragma unroll
        for (int reg = 0; reg < 4; ++reg)
            Xh[(r0 + quad * 4 + reg) * LDH + nt * 16 + n16] = (_Float16)acc[nt][reg];
    {
        int r = r0 + (l >> 2);
        int o = (l & 3) * 16;
        if (nb + r < N) {
            half8 v0 = *(const half8*)(Xh + r * LDH + o);
            half8 v1 = *(const half8*)(Xh + r * LDH + o + 8);
            *(half8*)(Hh + (size_t)(nb + r) * 64 + o) = v0;
            *(half8*)(Hh + (size_t)(nb + r) * 64 + o + 8) = v1;
        }
    }
}

// ---------------------------------------------------------------------------
// Dispatch 1: blocks [0, nblk) bucket_count; rest gemm layer-1; resets ticket.
// ---------------------------------------------------------------------------
__global__ __launch_bounds__(256)
void gemm1_and_count(const float* __restrict__ X, const float* __restrict__ W,
                     const float* __restrict__ ASRC, const float* __restrict__ ADST,
                     _Float16* __restrict__ Hh, float* __restrict__ AS,
                     float* __restrict__ AD, int N,
                     const int* __restrict__ dst, int E, int nblk, int nbuck,
                     int* __restrict__ cnts, int* __restrict__ ticket) {
    constexpr int K = FIN, LDH = K + 8;
    __shared__ _Float16 Xh[64 * LDH];
    __shared__ _Float16 WT[64 * LDH];

    const int tid = threadIdx.x;
    if ((int)blockIdx.x < nblk) {
        int* hist = (int*)Xh;
        if (blockIdx.x == 0 && tid == 0) *ticket = 0;
        for (int i = tid; i < nbuck; i += 256) hist[i] = 0;
        __syncthreads();
        int e0 = blockIdx.x * EPB;
        int e1 = min(e0 + EPB, E);
        for (int e = e0 + tid; e < e1; e += 256)
            atomicAdd(&hist[dst[e] >> BSH], 1);
        __syncthreads();
        for (int i = tid; i < nbuck; i += 256)
            cnts[blockIdx.x * nbuck + i] = hist[i];
        return;
    }
    gemm_mfma_body<K, float>(X, W, ASRC, ADST, Hh, AS, AD, N,
                             blockIdx.x - nblk, Xh, WT);
}

template <int K, typename XT>
__global__ __launch_bounds__(256)
void gemm_feat(const XT* __restrict__ X, const float* __restrict__ W,
               const float* __restrict__ ASRC, const float* __restrict__ ADST,
               _Float16* __restrict__ Hh, float* __restrict__ AS,
               float* __restrict__ AD, int N) {
    constexpr int LDH = K + 8;
    __shared__ _Float16 Xh[64 * LDH];
    __shared__ _Float16 WT[64 * LDH];
    gemm_mfma_body<K, XT>(X, W, ASRC, ADST, Hh, AS, AD, N, blockIdx.x, Xh, WT);
}

// ---------------------------------------------------------------------------
// Chunked column scan of cnts (nblk can exceed 256) + fused bucket-base scan
// in the last-arriving block (device-scope atomics for cross-XCD publish).
// ---------------------------------------------------------------------------
__global__ __launch_bounds__(256)
void bucket_colscan_fused(int* __restrict__ cnts, int nblk, int nbuck,
                          int* __restrict__ btotal, int* __restrict__ bbase,
                          int* __restrict__ ticket) {
    __shared__ int wsums[4];
    __shared__ int lastflag;
    int b = blockIdx.x;
    int tid = threadIdx.x;
    int carry = 0;
    for (int c0 = 0; c0 < nblk; c0 += 256) {
        int t = c0 + tid;
        int v = (t < nblk) ? cnts[t * nbuck + b] : 0;
        int tot;
        int e = block_scan_tot(v, tid, wsums, &tot);
        if (t < nblk) cnts[t * nbuck + b] = e + carry;
        carry += tot;
        __syncthreads();
    }
    if (tid == 0) {
        atomicExch(&btotal[b], carry);
        int old = atomicAdd(ticket, 1);
        lastflag = (old == nbuck - 1);
    }
    __syncthreads();
    if (!lastflag) return;
    int i0 = 2 * tid, i1 = 2 * tid + 1;
    int v0 = (i0 < nbuck) ? atomicAdd(&btotal[i0], 0) : 0;
    int v1 = (i1 < nbuck) ? atomicAdd(&btotal[i1], 0) : 0;
    __syncthreads();
    int tot2;
    int e2 = block_scan_tot(v0 + v1, tid, wsums, &tot2);
    if (i0 <= nbuck) bbase[i0] = e2;
    if (i1 <= nbuck) bbase[i1] = e2 + v0;
}

__global__ __launch_bounds__(256)
void bucket_scatter(const int* __restrict__ src, const int* __restrict__ dst,
                    int E, int nbuck, const int* __restrict__ cnts,
                    const int* __restrict__ bbase, int* __restrict__ ebuck) {
    __shared__ int cur[512];
    int tid = threadIdx.x;
    for (int i = tid; i < nbuck; i += 256)
        cur[i] = bbase[i] + cnts[blockIdx.x * nbuck + i];
    __syncthreads();
    int e0 = blockIdx.x * EPB;
    int e1 = min(e0 + EPB, E);
    for (int e = e0 + tid; e < e1; e += 256) {
        int d = dst[e];
        int p = atomicAdd(&cur[d >> BSH], 1);
        ebuck[p] = ((d & (NPB - 1)) << PACK_SH) | src[e];
    }
}

__global__ __launch_bounds__(256)
void bucket_to_csr(const int* __restrict__ ebuck, const int* __restrict__ bbase,
                   int N, int E, int* __restrict__ row_ptr,
                   int* __restrict__ csr_src) {
    __shared__ int hist[NPB];
    __shared__ int cur[NPB];
    __shared__ int wsums[4];
    int b = blockIdx.x, tid = threadIdx.x;
    int nstart = b << BSH;
    int base = bbase[b], endp = bbase[b + 1];
    if (tid < NPB) hist[tid] = 0;
    __syncthreads();
    for (int e = base + tid; e < endp; e += 256)
        atomicAdd(&hist[((unsigned)ebuck[e]) >> PACK_SH], 1);
    __syncthreads();
    int v = (tid < NPB) ? hist[tid] : 0;
    int tot;
    int excl = block_scan_tot(v, tid, wsums, &tot);
    if (tid < NPB) {
        cur[tid] = excl;
        if (nstart + tid < N) row_ptr[nstart + tid] = base + excl;
    }
    if (b == 0 && tid == 0) row_ptr[N] = E;
    __syncthreads();
    for (int e = base + tid; e < endp; e += 256) {
        int pv = ebuck[e];
        int p = atomicAdd(&cur[((unsigned)pv) >> PACK_SH], 1);
        csr_src[base + p] = pv & ((1 << PACK_SH) - 1);
    }
}

// ---------------------------------------------------------------------------
// Full-wave single-node aggregation (fallback for deg > 32; also handles the
// rare deg > 64 scalar path). Identical math to the R7 kernel.
// ---------------------------------------------------------------------------
template <typename OT>
__device__ __forceinline__
void agg_one_node(const _Float16* __restrict__ Hh, const float* __restrict__ AS,
                  const float* __restrict__ AD, const int* __restrict__ csr_src,
                  const float* __restrict__ bias, OT* __restrict__ OUT,
                  int n, int base, int end, int lane, int relu) {
    const int cnt = end - base;
    const float adn = AD[n];

    if (cnt > 64) {   // rare slow path (scalar, 2-pass, keeps max for safety)
        float m = -INFINITY;
        for (int c0 = base; c0 < end; c0 += 64) {
            int c = min(64, end - c0);
            float e = -INFINITY;
            if (lane < c) {
                int sr = csr_src[c0 + lane];
                float t = AS[sr] + adn;
                e = t > 0.f ? t : 0.2f * t;
            }
#pragma unroll
            for (int off = 32; off > 0; off >>= 1) e = fmaxf(e, __shfl_xor(e, off, 64));
            m = fmaxf(m, e);
        }
        float s = 0.f, acc = 0.f;
        for (int c0 = base; c0 < end; c0 += 64) {
            int c = min(64, end - c0);
            int srcl = 0;
            float p = 0.f;
            if (lane < c) {
                srcl = csr_src[c0 + lane];
                float t = AS[srcl] + adn;
                t = t > 0.f ? t : 0.2f * t;
                p = __expf(t - m);
            }
            float cs = p;
#pragma unroll
            for (int off = 32; off > 0; off >>= 1) cs += __shfl_xor(cs, off, 64);
            s += cs;
            for (int j = 0; j < c; ++j)
                acc += __shfl(p, j, 64) *
                       (float)Hh[(size_t)__shfl(srcl, j, 64) * 64 + lane];
        }
        float o = acc * (1.f / (s + 1e-16f)) + bias[lane];
        if (relu) o = fmaxf(o, 0.f);
        OUT[(size_t)n * 64 + lane] = (OT)o;
        return;
    }

    // ---- full-wave fast path: deg <= 64 ----
    int srcl = 0;
    float el = 0.f;
    if (lane < cnt) {
        srcl = csr_src[base + lane];          // coalesced
        float e = AS[srcl] + adn;             // 4B gather (L2-hot)
        el = e > 0.f ? e : 0.2f * e;          // LeakyReLU(0.2)
    }
    float p = (lane < cnt) ? __expf(el) : 0.f;   // no max-subtract (|e| small)
    float s = p;
#pragma unroll
    for (int off = 32; off > 0; off >>= 1) s += __shfl_xor(s, off, 64);
    const float inv = 1.f / (s + 1e-16f);

    const int eg = lane >> 3;                 // edge slot 0..7
    const int c8 = (lane & 7) * 8;            // channel base (8 ch/lane)

    float acc[8], acc2[8];
#pragma unroll
    for (int t = 0; t < 8; ++t) { acc[t] = 0.f; acc2[t] = 0.f; }

    int j = 0;
    for (; j + 16 <= cnt; j += 16) {          // 16 edges in flight
        int iA = j + eg, iB = j + 8 + eg;
        int sA = __shfl(srcl, iA, 64), sB = __shfl(srcl, iB, 64);
        float aA = __shfl(p, iA, 64),  aB = __shfl(p, iB, 64);
        half8 hA = *(const half8*)(Hh + (size_t)sA * 64 + c8);
        half8 hB = *(const half8*)(Hh + (size_t)sB * 64 + c8);
#pragma unroll
        for (int t = 0; t < 8; ++t) {
            acc[t]  += aA * (float)hA[t];
            acc2[t] += aB * (float)hB[t];
        }
    }
    for (; j < cnt; j += 8) {                 // tail volley (p=0 kills extras)
        int iA = j + eg;
        int sA = __shfl(srcl, iA, 64);
        float aA = __shfl(p, iA, 64);
        half8 hA = *(const half8*)(Hh + (size_t)sA * 64 + c8);
#pragma unroll
        for (int t = 0; t < 8; ++t) acc[t] += aA * (float)hA[t];
    }
#pragma unroll
    for (int t = 0; t < 8; ++t) acc[t] += acc2[t];
#pragma unroll
    for (int off = 8; off <= 32; off <<= 1)
#pragma unroll
        for (int t = 0; t < 8; ++t) acc[t] += __shfl_xor(acc[t], off, 64);

    if (lane < 8) {
        float4 b0 = *(const float4*)(bias + c8);
        float4 b1 = *(const float4*)(bias + c8 + 4);
        float o[8];
        o[0] = acc[0] * inv + b0.x; o[1] = acc[1] * inv + b0.y;
        o[2] = acc[2] * inv + b0.z; o[3] = acc[3] * inv + b0.w;
        o[4] = acc[4] * inv + b1.x; o[5] = acc[5] * inv + b1.y;
        o[6] = acc[6] * inv + b1.z; o[7] = acc[7] * inv + b1.w;
        if (relu) {
#pragma unroll
            for (int t = 0; t < 8; ++t) o[t] = fmaxf(o[t], 0.f);
        }
        if constexpr (sizeof(OT) == 2) {
            half8 hv;
#pragma unroll
            for (int t = 0; t < 8; ++t) hv[t] = (_Float16)o[t];
            *(half8*)((_Float16*)OUT + (size_t)n * 64 + c8) = hv;
        } else {
            *(float4*)((float*)OUT + (size_t)n * 64 + c8) =
                make_float4(o[0], o[1], o[2], o[3]);
            *(float4*)((float*)OUT + (size_t)n * 64 + c8 + 4) =
                make_float4(o[4], o[5], o[6], o[7]);
        }
    }
}

// ---------------------------------------------------------------------------
// Fused softmax + aggregate (R8): TWO nodes per wave (half-wave per node)
// when both degrees <= 32 (P[deg>32] ~ 1.4e-4 at Poisson(16)). Halves wave
// count and cuts cross-lane (ds_bpermute) ops per node ~2.3x:
//  - softmax reduce: 5 xor stages (shared by both nodes) vs 6 per node
//  - final reduce: 2 stages x 8 accs vs 3 stages x 8 per node
//  - tail gather overshoot: 4-edge slots vs 8 (less wasted L2/L3 traffic)
// Rare fallback: full-wave per node (agg_one_node), same math as R7.
// ---------------------------------------------------------------------------
template <typename OT>
__global__ __launch_bounds__(256)
void gat_aggregate(const _Float16* __restrict__ Hh, const float* __restrict__ AS,
                   const float* __restrict__ AD, const int* __restrict__ row_ptr,
                   const int* __restrict__ csr_src, const float* __restrict__ bias,
                   OT* __restrict__ OUT, int N, int relu) {
    const int lane = threadIdx.x & 63;
    const int half = lane >> 5;            // 0: node A, 1: node B
    const int l32  = lane & 31;
    const int pair0 = blockIdx.x * 8 + (threadIdx.x >> 6) * 2;
    if (pair0 >= N) return;
    const int n = pair0 + half;

    int base = 0, end = 0;
    if (n < N) { base = row_ptr[n]; end = row_ptr[n + 1]; }
    const int cnt = end - base;

    if (!__all(cnt <= 32)) {
        // rare: at least one of the pair has deg > 32 -> full-wave per node
        int baseA = __shfl(base, 0, 64),  endA = __shfl(end, 0, 64);
        int baseB = __shfl(base, 32, 64), endB = __shfl(end, 32, 64);
        agg_one_node(Hh, AS, AD, csr_src, bias, OUT, pair0, baseA, endA, lane, relu);
        if (pair0 + 1 < N)
            agg_one_node(Hh, AS, AD, csr_src, bias, OUT, pair0 + 1, baseB, endB,
                         lane, relu);
        return;
    }

    // ---- paired fast path: both deg <= 32, half-wave per node ----
    const float adn = (n < N) ? AD[n] : 0.f;
    int srcl = 0;
    float p = 0.f;
    if (l32 < cnt) {
        srcl = csr_src[base + l32];           // coalesced per half
        float e = AS[srcl] + adn;             // 4B gather (L2-hot)
        e = e > 0.f ? e : 0.2f * e;           // LeakyReLU(0.2)
        p = __expf(e);                        // no max-subtract (|e| small)
    }
    float s = p;
#pragma unroll
    for (int off = 16; off > 0; off >>= 1) s += __shfl_xor(s, off, 64);
    const float inv = 1.f / (s + 1e-16f);

    const int eg = l32 >> 3;                  // edge slot 0..3 (within half)
    const int c8 = (l32 & 7) * 8;             // channel base (8 ch/lane)

    float acc[8], acc2[8];
#pragma unroll
    for (int t = 0; t < 8; ++t) { acc[t] = 0.f; acc2[t] = 0.f; }

    int j = 0;
    for (; j + 8 <= cnt; j += 8) {            // 8 edges in flight per node
        int iA = j + eg, iB = j + 4 + eg;
        int sA = __shfl(srcl, iA, 32), sB = __shfl(srcl, iB, 32);
        float aA = __shfl(p, iA, 32),  aB = __shfl(p, iB, 32);
        half8 hA = *(const half8*)(Hh + (size_t)sA * 64 + c8);
        half8 hB = *(const half8*)(Hh + (size_t)sB * 64 + c8);
#pragma unroll
        for (int t = 0; t < 8; ++t) {
            acc[t]  += aA * (float)hA[t];
            acc2[t] += aB * (float)hB[t];
        }
    }
    for (; j < cnt; j += 4) {                 // tail volley (p=0 kills extras)
        int iA = j + eg;
        int sA = __shfl(srcl, iA, 32);
        float aA = __shfl(p, iA, 32);
        half8 hA = *(const half8*)(Hh + (size_t)sA * 64 + c8);
#pragma unroll
        for (int t = 0; t < 8; ++t) acc[t] += aA * (float)hA[t];
    }
#pragma unroll
    for (int t = 0; t < 8; ++t) acc[t] += acc2[t];
    // reduce over 4 edge slots (strides 8, 16 stay within the half-wave)
#pragma unroll
    for (int t = 0; t < 8; ++t) acc[t] += __shfl_xor(acc[t], 8, 64);
#pragma unroll
    for (int t = 0; t < 8; ++t) acc[t] += __shfl_xor(acc[t], 16, 64);

    if (l32 < 8 && n < N) {
        float4 b0 = *(const float4*)(bias + c8);
        float4 b1 = *(const float4*)(bias + c8 + 4);
        float o[8];
        o[0] = acc[0] * inv + b0.x; o[1] = acc[1] * inv + b0.y;
        o[2] = acc[2] * inv + b0.z; o[3] = acc[3] * inv + b0.w;
        o[4] = acc[4] * inv + b1.x; o[5] = acc[5] * inv + b1.y;
        o[6] = acc[6] * inv + b1.z; o[7] = acc[7] * inv + b1.w;
        if (relu) {
#pragma unroll
            for (int t = 0; t < 8; ++t) o[t] = fmaxf(o[t], 0.f);
        }
        if constexpr (sizeof(OT) == 2) {
            half8 hv;
#pragma unroll
            for (int t = 0; t < 8; ++t) hv[t] = (_Float16)o[t];
            *(half8*)((_Float16*)OUT + (size_t)n * 64 + c8) = hv;
        } else {
            *(float4*)((float*)OUT + (size_t)n * 64 + c8) =
                make_float4(o[0], o[1], o[2], o[3]);
            *(float4*)((float*)OUT + (size_t)n * 64 + c8 + 4) =
                make_float4(o[4], o[5], o[6], o[7]);
        }
    }
}

// ---------------------------------------------------------------------------
extern "C" void kernel_launch(void* const* d_in, const int* in_sizes, int n_in,
                              void* d_out, int out_size, void* d_ws, size_t ws_size,
                              hipStream_t stream) {
    const float* x    = (const float*)d_in[0];
    const int*   ei   = (const int*)d_in[1];
    const float* W1   = (const float*)d_in[2];
    const float* as1w = (const float*)d_in[3];
    const float* ad1w = (const float*)d_in[4];
    const float* b1   = (const float*)d_in[5];
    const float* W2   = (const float*)d_in[6];
    const float* as2w = (const float*)d_in[7];
    const float* ad2w = (const float*)d_in[8];
    const float* b2   = (const float*)d_in[9];
    float* out = (float*)d_out;

    const int N = in_sizes[0] / FIN;   // 50000
    const int E = in_sizes[1] / 2;     // 800000
    const int* esrc = ei;
    const int* edst = ei + E;

    const int nbuck = (N + NPB - 1) >> BSH;      // 391 (<= 512)
    const int nblk  = (E + EPB - 1) / EPB;       // 391

    // Workspace layout (~22 MB, no aliasing)
    char* wp8 = (char*)d_ws;
    _Float16* Hh  = (_Float16*)wp8;  wp8 += (size_t)N * 64 * 2;
    _Float16* R1h = (_Float16*)wp8;  wp8 += (size_t)N * 64 * 2;
    float* AS1 = (float*)wp8;        wp8 += (size_t)N * 4;
    float* AD1 = (float*)wp8;        wp8 += (size_t)N * 4;
    float* AS2 = (float*)wp8;        wp8 += (size_t)N * 4;
    float* AD2 = (float*)wp8;        wp8 += (size_t)N * 4;
    int* row_ptr = (int*)wp8;        wp8 += (size_t)(N + 1) * 4;
    int* csr     = (int*)wp8;        wp8 += (size_t)E * 4;
    int* ebuck   = (int*)wp8;        wp8 += (size_t)E * 4;
    int* cnts    = (int*)wp8;        wp8 += (size_t)nblk * nbuck * 4;
    int* btotal  = (int*)wp8;        wp8 += (size_t)nbuck * 4;
    int* bbase   = (int*)wp8;        wp8 += (size_t)(nbuck + 1) * 4;
    int* ticket  = (int*)wp8;        wp8 += 4;

    const int nbG = (N + 63) / 64;               // 782
    const int nbAgg = (N + 7) / 8;               // 6250 (2 nodes/wave)

    // 1) fused: bucket_count (391 blocks) + MFMA gemm layer-1 (+ ticket reset)
    hipLaunchKernelGGL(gemm1_and_count, dim3(nblk + nbG), dim3(256), 0, stream,
                       x, W1, as1w, ad1w, Hh, AS1, AD1, N,
                       edst, E, nblk, nbuck, cnts, ticket);
    // 2) chunked column scan + fused bucket-base scan
    hipLaunchKernelGGL(bucket_colscan_fused, dim3(nbuck), dim3(256), 0, stream,
                       cnts, nblk, nbuck, btotal, bbase, ticket);
    // 3) scatter into buckets (391 blocks — full CU coverage)
    hipLaunchKernelGGL(bucket_scatter, dim3(nblk), dim3(256), 0, stream,
                       esrc, edst, E, nbuck, cnts, bbase, ebuck);
    // 4) bucket -> CSR
    hipLaunchKernelGGL(bucket_to_csr, dim3(nbuck), dim3(256), 0, stream,
                       ebuck, bbase, N, E, row_ptr, csr);
    // 5) aggregate layer-1 (fp16 out)
    hipLaunchKernelGGL(gat_aggregate<_Float16>, dim3(nbAgg), dim3(256), 0,
                       stream, Hh, AS1, AD1, row_ptr, csr, b1, R1h, N, 1);
    // 6) MFMA gemm layer-2 (fp16 in)
    hipLaunchKernelGGL((gemm_feat<64, _Float16>), dim3(nbG), dim3(256), 0, stream,
                       R1h, W2, as2w, ad2w, Hh, AS2, AD2, N);
    // 7) aggregate layer-2 (fp32 out)
    hipLaunchKernelGGL(gat_aggregate<float>, dim3(nbAgg), dim3(256), 0,
                       stream, Hh, AS2, AD2, row_ptr, csr, b2, out, N, 0);
}